// Round 10
// baseline (2708.120 us; speedup 1.0000x reference)
//
#include <hip/hip_runtime.h>

#define B_ 8
#define N_ 4096
#define K_ 1024
#define NN_ 16
#define C1_ 128
#define C2_ 128
#define CIN_ 67
#define NROWS (B_*K_*NN_)   // 131072
#define NBLK  (NROWS/64)    // 2048 GEMM tiles
#define BN_N 131072.0f

typedef unsigned short u16;

// ROOT CAUSE of rounds 1-6/8 aborts: inputs/outputs are FLOAT32 (per the
// reference), not bf16. Reading f32 as u16 made NaN centers -> kNN sentinel
// index 0x7fffffff -> OOB gather -> GPU page fault. This build is all-f32.
__device__ u16   g_knn[NROWS];
__device__ float g_part1[NBLK*256];
__device__ float g_part2[NBLK*256];
__device__ float g_stats[512];
__device__ float g_m2[B_*K_*C2_];

// ---------------------------------------------------------------- FPS ------
// One 256-thread block per batch; 16 points/thread in registers; block-wide
// argmax via scalar LDS tree. Tie-break: smaller index (jnp.argmax). f32
// math, contract-off, same evaluation order as the np reference.
__global__ __launch_bounds__(256) void fps_kernel(const float* __restrict__ xyz,
                                                  float* __restrict__ out_xyz) {
    __shared__ float cen[3];
    __shared__ float tv[256];
    __shared__ int   ti[256];
    const int b = blockIdx.x, t = threadIdx.x;
    const float* xb = xyz + b * (N_ * 3);
    float x0[16], y0[16], z0[16], dist[16];
    #pragma unroll
    for (int j = 0; j < 16; ++j) {
        int p = t * 16 + j;
        x0[j] = xb[p*3+0]; y0[j] = xb[p*3+1]; z0[j] = xb[p*3+2];
        dist[j] = 1e10f;
    }
    int far = 0;
    for (int s = 0; s < K_; ++s) {
        if (t == 0) {
            int o = (b*K_ + s) * 3;
            out_xyz[o+0] = xb[far*3+0];
            out_xyz[o+1] = xb[far*3+1];
            out_xyz[o+2] = xb[far*3+2];
        }
        if (t == (far >> 4)) {
            cen[0] = xb[far*3+0];
            cen[1] = xb[far*3+1];
            cen[2] = xb[far*3+2];
        }
        __syncthreads();                       // cen visible
        const float cx = cen[0], cy = cen[1], cz = cen[2];
        {
            #pragma clang fp contract(off)
            #pragma unroll
            for (int j = 0; j < 16; ++j) {
                float dx = x0[j]-cx, dy = y0[j]-cy, dz = z0[j]-cz;
                float dd = dx*dx; dd = dd + dy*dy; dd = dd + dz*dz;
                dist[j] = fminf(dist[j], dd);
            }
        }
        float v = dist[0]; int ib = t * 16;
        #pragma unroll
        for (int j = 1; j < 16; ++j)
            if (dist[j] > v) { v = dist[j]; ib = t*16 + j; }   // strict >: first max
        tv[t] = v; ti[t] = ib;
        __syncthreads();
        for (int st = 128; st > 0; st >>= 1) {
            if (t < st) {
                float ov = tv[t+st]; int oi = ti[t+st];
                if (ov > tv[t] || (ov == tv[t] && oi < ti[t])) { tv[t] = ov; ti[t] = oi; }
            }
            __syncthreads();
        }
        far = ti[0] & 4095;   // provably in-range; clamp is fault insurance
    }
}

// ---------------------------------------------------------------- kNN ------
// One 256-thread block per sampled center (grid 1024 x 8); 16 points/thread;
// 16 rounds of lexicographic-(d, idx) min extraction via scalar LDS tree
// (matches stable top_k ties). Distance formula matches np: (sn+sp) - 2*dot,
// sequential, no FMA.
__global__ __launch_bounds__(256) void knn_kernel(const float* __restrict__ xyz,
                                                  const float* __restrict__ newxyz) {
    __shared__ float tv[256];
    __shared__ int   ti[256];
    const int k = blockIdx.x, b = blockIdx.y, t = threadIdx.x;
    const int m = b*K_ + k;
    const float* xb = xyz + b * (N_ * 3);
    const float cx = newxyz[m*3+0];
    const float cy = newxyz[m*3+1];
    const float cz = newxyz[m*3+2];
    float d[16];
    {
        #pragma clang fp contract(off)
        float sn = cx*cx; sn = sn + cy*cy; sn = sn + cz*cz;
        #pragma unroll
        for (int j = 0; j < 16; ++j) {
            int p = j*256 + t;
            float X = xb[p*3+0], Y = xb[p*3+1], Z = xb[p*3+2];
            float sp = X*X; sp = sp + Y*Y; sp = sp + Z*Z;
            float dt = cx*X; dt = dt + cy*Y; dt = dt + cz*Z;
            float t1 = sn + sp;
            d[j] = t1 - 2.0f*dt;
        }
    }
    float prevd = -1e38f; int previ = -1;
    for (int r = 0; r < NN_; ++r) {
        float bv = 1e38f; int bi = 0x7fffffff;
        #pragma unroll
        for (int j = 0; j < 16; ++j) {
            int p = j*256 + t;
            bool gt = (d[j] > prevd) || (d[j] == prevd && p > previ);
            bool lt = (d[j] < bv)   || (d[j] == bv   && p < bi);
            if (gt && lt) { bv = d[j]; bi = p; }
        }
        tv[t] = bv; ti[t] = bi;
        __syncthreads();
        for (int st = 128; st > 0; st >>= 1) {
            if (t < st) {
                float ov = tv[t+st]; int oi = ti[t+st];
                if (ov < tv[t] || (ov == tv[t] && oi < ti[t])) { tv[t] = ov; ti[t] = oi; }
            }
            __syncthreads();
        }
        bv = tv[0]; bi = ti[0];
        if (t == 0) g_knn[m*NN_ + r] = (u16)(bi & 4095);
        prevd = bv; previ = bi;
        __syncthreads();   // WAR: reads of tv/ti done before next round's writes
    }
}

// ------------------------------------------------- GEMM1 stats pass --------
// Pre-BN h1 (64-row tile x 128 ch); W1 streamed from global (34 KB, L1-hot,
// broadcast across lanes); per-channel sum/sumsq partials -> g_part1.
__global__ __launch_bounds__(256) void stats1_kernel(
        const float* __restrict__ xyz, const float* __restrict__ points,
        const float* __restrict__ newxyz,
        const float* __restrict__ W1, const float* __restrict__ b1) {
    __shared__ float Xs[64][68];
    __shared__ float ps[16][128], pq[16][128];
    __shared__ float cen[4][3];
    __shared__ int rowp[64];
    const int t = threadIdx.x;
    const int blk = blockIdx.x;
    const int b = blk >> 8;
    const int g0 = blk * 64;
    if (t < 64)  rowp[t] = ((int)g_knn[g0 + t]) & 4095;
    if (t < 12)  cen[t/3][t%3] = newxyz[(blk*4 + t/3)*3 + (t%3)];
    __syncthreads();
    for (int e = t; e < 64*68; e += 256) {
        int r = e / 68, c = e % 68;
        int p = rowp[r];
        float v = 0.f;
        if (c < 3)         v = xyz[(b*N_ + p)*3 + c] - cen[r >> 4][c];
        else if (c < CIN_) v = points[(b*N_ + p)*64 + (c - 3)];
        Xs[r][c] = v;
    }
    __syncthreads();
    const int rg = t >> 4, cg = t & 15;
    const int r0 = rg * 4;
    float acc[4][8];
    #pragma unroll
    for (int j = 0; j < 4; ++j)
        #pragma unroll
        for (int i = 0; i < 8; ++i) acc[j][i] = 0.f;
    for (int q = 0; q < CIN_; ++q) {
        float xq[4];
        #pragma unroll
        for (int j = 0; j < 4; ++j) xq[j] = Xs[r0 + j][q];
        #pragma unroll
        for (int i = 0; i < 8; ++i) {
            float wv = W1[(cg + 16*i)*CIN_ + q];
            #pragma unroll
            for (int j = 0; j < 4; ++j) acc[j][i] += xq[j] * wv;
        }
    }
    #pragma unroll
    for (int i = 0; i < 8; ++i) {
        int o = cg + 16*i;
        float bias = b1[o];
        float s = 0.f, sq = 0.f;
        #pragma unroll
        for (int j = 0; j < 4; ++j) {
            float v = acc[j][i] + bias;
            s += v; sq += v*v;
        }
        ps[rg][o] = s; pq[rg][o] = sq;   // unique (rg,o) per thread
    }
    __syncthreads();
    if (t < 128) {
        float ts = 0.f, tq = 0.f;
        #pragma unroll
        for (int g = 0; g < 16; ++g) { ts += ps[g][t]; tq += pq[g][t]; }
        g_part1[blk*256 + t] = ts;
        g_part1[blk*256 + 128 + t] = tq;
    }
}

// ------------------------------------------------------------ reduce -------
__global__ __launch_bounds__(256) void reduce1_kernel() {
    __shared__ float red[256];
    const int i = blockIdx.x, t = threadIdx.x;
    float s = 0.f;
    for (int r = t; r < NBLK; r += 256) s += g_part1[r*256 + i];
    red[t] = s;
    __syncthreads();
    for (int st = 128; st > 0; st >>= 1) {
        if (t < st) red[t] += red[t + st];
        __syncthreads();
    }
    if (t == 0) g_stats[i] = red[0];
}
__global__ __launch_bounds__(256) void reduce2_kernel() {
    __shared__ float red[256];
    const int i = blockIdx.x, t = threadIdx.x;
    float s = 0.f;
    for (int r = t; r < NBLK; r += 256) s += g_part2[r*256 + i];
    red[t] = s;
    __syncthreads();
    for (int st = 128; st > 0; st >>= 1) {
        if (t < st) red[t] += red[t + st];
        __syncthreads();
    }
    if (t == 0) g_stats[256 + i] = red[0];
}

// --------------------------------------------- fused GEMM1+BN1+GEMM2 -------
// Recompute GEMM1 tile (W1 streamed), BN1+ReLU (global stats, consts read
// from global per channel) -> f32 h1 tile in LDS -> GEMM2 (W2 streamed,
// 64 KB L2-resident). Epilogue: BN2 partials -> g_part2; per-group (16-row)
// max of pre-BN h2 -> g_m2 (BN2+ReLU monotone: g2=1>0, max commutes).
__global__ __launch_bounds__(256) void fused12_kernel(
        const float* __restrict__ xyz, const float* __restrict__ points,
        const float* __restrict__ newxyz,
        const float* __restrict__ W1, const float* __restrict__ b1,
        const float* __restrict__ g1, const float* __restrict__ be1,
        const float* __restrict__ W2, const float* __restrict__ b2) {
    __shared__ union {
        float Xs[64][68];                                                 // 17408 B
        struct { float ps[16][128], pq[16][128], pm[16][128]; } c;        // 24576 B
    } u;
    __shared__ float h1s[64][128];                                        // 32768 B
    __shared__ float cen[4][3];
    __shared__ int rowp[64];
    const int t = threadIdx.x;
    const int blk = blockIdx.x;
    const int b = blk >> 8;
    const int g0 = blk * 64;
    if (t < 64)  rowp[t] = ((int)g_knn[g0 + t]) & 4095;
    if (t < 12)  cen[t/3][t%3] = newxyz[(blk*4 + t/3)*3 + (t%3)];
    __syncthreads();
    for (int e = t; e < 64*68; e += 256) {
        int r = e / 68, c = e % 68;
        int p = rowp[r];
        float v = 0.f;
        if (c < 3)         v = xyz[(b*N_ + p)*3 + c] - cen[r >> 4][c];
        else if (c < CIN_) v = points[(b*N_ + p)*64 + (c - 3)];
        u.Xs[r][c] = v;
    }
    __syncthreads();
    const int rg = t >> 4, cg = t & 15;
    const int r0 = rg * 4;
    // ---- GEMM1 ----
    float acc[4][8];
    #pragma unroll
    for (int j = 0; j < 4; ++j)
        #pragma unroll
        for (int i = 0; i < 8; ++i) acc[j][i] = 0.f;
    for (int q = 0; q < CIN_; ++q) {
        float xq[4];
        #pragma unroll
        for (int j = 0; j < 4; ++j) xq[j] = u.Xs[r0 + j][q];
        #pragma unroll
        for (int i = 0; i < 8; ++i) {
            float wv = W1[(cg + 16*i)*CIN_ + q];
            #pragma unroll
            for (int j = 0; j < 4; ++j) acc[j][i] += xq[j] * wv;
        }
    }
    // BN1 + ReLU -> f32 h1 tile (consts derived from global stats per channel)
    #pragma unroll
    for (int i = 0; i < 8; ++i) {
        int o = cg + 16*i;
        float mean = g_stats[o] * (1.f / BN_N);
        float var  = g_stats[128 + o] * (1.f / BN_N) - mean*mean;
        float sc   = (1.f / sqrtf(var + 1e-5f)) * g1[o];
        float bb   = be1[o];
        float bias = b1[o];
        #pragma unroll
        for (int j = 0; j < 4; ++j) {
            float v = acc[j][i] + bias;
            v = (v - mean) * sc + bb;
            v = fmaxf(v, 0.f);
            h1s[r0 + j][o] = v;
        }
    }
    __syncthreads();   // Xs reads done + h1s visible
    // ---- GEMM2 ----
    float acc2[4][8];
    #pragma unroll
    for (int j = 0; j < 4; ++j)
        #pragma unroll
        for (int i = 0; i < 8; ++i) acc2[j][i] = 0.f;
    for (int q = 0; q < C1_; ++q) {
        float xq[4];
        #pragma unroll
        for (int j = 0; j < 4; ++j) xq[j] = h1s[r0 + j][q];
        #pragma unroll
        for (int i = 0; i < 8; ++i) {
            float wv = W2[(cg + 16*i)*C1_ + q];
            #pragma unroll
            for (int j = 0; j < 4; ++j) acc2[j][i] += xq[j] * wv;
        }
    }
    // Epilogue: partials into the union region (Xs dead since the barrier)
    #pragma unroll
    for (int i = 0; i < 8; ++i) {
        int o = cg + 16*i;
        float bias = b2[o];
        float s = 0.f, sq = 0.f, mx = -1e38f;
        #pragma unroll
        for (int j = 0; j < 4; ++j) {
            float v = acc2[j][i] + bias;
            s += v; sq += v*v; mx = fmaxf(mx, v);
        }
        u.c.ps[rg][o] = s; u.c.pq[rg][o] = sq; u.c.pm[rg][o] = mx;
    }
    __syncthreads();
    if (t < 128) {
        float ts = 0.f, tq = 0.f;
        #pragma unroll
        for (int g = 0; g < 16; ++g) { ts += u.c.ps[g][t]; tq += u.c.pq[g][t]; }
        g_part2[blk*256 + t] = ts;
        g_part2[blk*256 + 128 + t] = tq;
    }
    {
        const int o = t & 127, gg = t >> 7;
        for (int gp = gg; gp < 4; gp += 2) {   // groups gg and gg+2
            float mx = u.c.pm[gp*4 + 0][o];
            mx = fmaxf(mx, u.c.pm[gp*4 + 1][o]);
            mx = fmaxf(mx, u.c.pm[gp*4 + 2][o]);
            mx = fmaxf(mx, u.c.pm[gp*4 + 3][o]);
            g_m2[(blk*4 + gp)*128 + o] = mx;
        }
    }
}

// ------------------------------------------------------------- finalize ----
__global__ __launch_bounds__(256) void final_kernel(
        const float* __restrict__ g2, const float* __restrict__ be2,
        float* __restrict__ outp) {
    __shared__ float mn[128], sc[128], bb[128];
    const int t = threadIdx.x;
    if (t < 128) {
        float mean = g_stats[256 + t] * (1.f / BN_N);
        float var  = g_stats[384 + t] * (1.f / BN_N) - mean*mean;
        float inv  = 1.f / sqrtf(var + 1e-5f);
        mn[t] = mean; sc[t] = inv * g2[t]; bb[t] = be2[t];
    }
    __syncthreads();
    const int m = blockIdx.x*2 + (t >> 7);
    const int c = t & 127;
    float v = (g_m2[m*128 + c] - mn[c]) * sc[c] + bb[c];
    v = fmaxf(v, 0.f);
    outp[m*C2_ + c] = v;
}

// -------------------------------------------------------------- launch -----
extern "C" void kernel_launch(void* const* d_in, const int* in_sizes, int n_in,
                              void* d_out, int out_size, void* d_ws, size_t ws_size,
                              hipStream_t stream) {
    const float* xyz    = (const float*)d_in[0];
    const float* points = (const float*)d_in[1];
    const float* W1     = (const float*)d_in[2];
    const float* b1     = (const float*)d_in[3];
    const float* g1     = (const float*)d_in[4];
    const float* be1    = (const float*)d_in[5];
    const float* W2     = (const float*)d_in[6];
    const float* b2     = (const float*)d_in[7];
    const float* g2     = (const float*)d_in[8];
    const float* be2    = (const float*)d_in[9];

    float* out_xyz = (float*)d_out;
    float* out_pts = (float*)d_out + B_*K_*3;

    (void)d_ws; (void)ws_size;   // scratch in __device__ globals

    fps_kernel<<<B_, 256, 0, stream>>>(xyz, out_xyz);
    knn_kernel<<<dim3(K_, B_), 256, 0, stream>>>(xyz, out_xyz);
    stats1_kernel<<<NBLK, 256, 0, stream>>>(xyz, points, out_xyz, W1, b1);
    reduce1_kernel<<<256, 256, 0, stream>>>();
    fused12_kernel<<<NBLK, 256, 0, stream>>>(xyz, points, out_xyz,
                                             W1, b1, g1, be1, W2, b2);
    reduce2_kernel<<<256, 256, 0, stream>>>();
    final_kernel<<<B_*K_/2, 256, 0, stream>>>(g2, be2, out_pts);
}

// Round 11
// 2419.566 us; speedup vs baseline: 1.1193x; 1.1193x over previous
//
#include <hip/hip_runtime.h>

#define B_ 8
#define N_ 4096
#define K_ 1024
#define NN_ 16
#define C1_ 128
#define C2_ 128
#define CIN_ 67
#define NROWS (B_*K_*NN_)   // 131072
#define NBLK  (NROWS/64)    // 2048 GEMM tiles
#define BN_N 131072.0f

typedef unsigned short u16;

__device__ u16   g_knn[NROWS];
__device__ float g_part1[NBLK*256];
__device__ float g_part2[NBLK*256];
__device__ float g_stats[512];
__device__ float g_m2[B_*K_*C2_];

// ---------------------------------------------------------------- FPS ------
// v2: 512 threads/block, one block per batch; 8 pts/thread in registers.
// Per step: local argmax -> 6-step shfl_xor wave reduce (no barrier) ->
// 8 wave partials in LDS -> barrier -> all threads redundantly reduce the 8
// partials and read the centroid from the LDS xyz copy -> barrier (WAR).
// 2 barriers/step vs round-10's 10 (3566 cyc/step measured, LDS-tree bound).
// Distance math: contract-off, mul/add order == np reference (bit-exact).
__global__ __launch_bounds__(512) void fps_kernel(const float* __restrict__ xyz,
                                                  float* __restrict__ out_xyz) {
    __shared__ float sx[N_*3];       // 48 KB xyz copy
    __shared__ float wv[8];
    __shared__ int   wi[8];
    const int b = blockIdx.x, t = threadIdx.x;
    const int l = t & 63, w = t >> 6;
    const float* xb = xyz + b * (N_ * 3);
    for (int e = t; e < N_*3; e += 512) sx[e] = xb[e];
    __syncthreads();
    float x0[8], y0[8], z0[8], dist[8];
    #pragma unroll
    for (int j = 0; j < 8; ++j) {
        int p = t * 8 + j;
        x0[j] = sx[p*3+0]; y0[j] = sx[p*3+1]; z0[j] = sx[p*3+2];
        dist[j] = 1e10f;
    }
    int far = 0;
    for (int s = 0; s < K_; ++s) {
        const float cx = sx[far*3+0], cy = sx[far*3+1], cz = sx[far*3+2];
        if (t == 0) {
            int o = (b*K_ + s) * 3;
            out_xyz[o+0] = cx; out_xyz[o+1] = cy; out_xyz[o+2] = cz;
        }
        float v = -1.f; int ib = 0;
        {
            #pragma clang fp contract(off)
            #pragma unroll
            for (int j = 0; j < 8; ++j) {
                float dx = x0[j]-cx, dy = y0[j]-cy, dz = z0[j]-cz;
                float dd = dx*dx; dd = dd + dy*dy; dd = dd + dz*dz;
                dd = fminf(dist[j], dd);
                dist[j] = dd;
                if (dd > v) { v = dd; ib = t*8 + j; }   // ascending j: first max
            }
        }
        #pragma unroll
        for (int off = 1; off <= 32; off <<= 1) {
            float ov = __shfl_xor(v, off);
            int   oi = __shfl_xor(ib, off);
            if (ov > v || (ov == v && oi < ib)) { v = ov; ib = oi; }
        }
        if (l == 0) { wv[w] = v; wi[w] = ib; }
        __syncthreads();                   // partials visible
        float bv = wv[0]; int bi = wi[0];
        #pragma unroll
        for (int ww = 1; ww < 8; ++ww) {
            float ov = wv[ww];
            if (ov > bv) { bv = ov; bi = wi[ww]; }   // waves cover ascending idx
        }
        far = bi & 4095;
        __syncthreads();                   // WAR: reads done before next writes
    }
}

// ---------------------------------------------------------------- kNN ------
// v2: one wave per center (4 waves/block, grid 256 x 8); 64 dists/lane in
// VGPRs; 16 rounds of lexicographic-(d, idx) min extraction via shfl
// butterfly — NO barriers in the extraction loop. Distance formula
// (sn+sp) - 2*dot, contract-off == np reference.
__global__ __launch_bounds__(256) void knn_kernel(const float* __restrict__ xyz,
                                                  const float* __restrict__ newxyz) {
    __shared__ float px[N_], py[N_], pz[N_];
    const int b = blockIdx.y, t = threadIdx.x;
    const int l = t & 63, w = t >> 6;
    const int k = blockIdx.x * 4 + w;
    const int m = b*K_ + k;
    const float* xb = xyz + b * (N_ * 3);
    for (int p = t; p < N_; p += 256) {
        px[p] = xb[p*3+0]; py[p] = xb[p*3+1]; pz[p] = xb[p*3+2];
    }
    __syncthreads();
    const float cx = newxyz[m*3+0];
    const float cy = newxyz[m*3+1];
    const float cz = newxyz[m*3+2];
    float d[64];
    {
        #pragma clang fp contract(off)
        float sn = cx*cx; sn = sn + cy*cy; sn = sn + cz*cz;
        #pragma unroll
        for (int j = 0; j < 64; ++j) {
            int p = j*64 + l;
            float X = px[p], Y = py[p], Z = pz[p];
            float sp = X*X; sp = sp + Y*Y; sp = sp + Z*Z;
            float dt = cx*X; dt = dt + cy*Y; dt = dt + cz*Z;
            float t1 = sn + sp;
            d[j] = t1 - 2.0f*dt;
        }
    }
    float prevd = -1e38f; int previ = -1;
    for (int r = 0; r < NN_; ++r) {
        float bv = 1e38f; int bi = 0x7fffffff;
        #pragma unroll
        for (int j = 0; j < 64; ++j) {
            int p = j*64 + l;
            bool gt = (d[j] > prevd) || (d[j] == prevd && p > previ);
            bool lt = (d[j] < bv)   || (d[j] == bv   && p < bi);
            if (gt && lt) { bv = d[j]; bi = p; }
        }
        #pragma unroll
        for (int off = 1; off <= 32; off <<= 1) {
            float ov = __shfl_xor(bv, off);
            int   oi = __shfl_xor(bi, off);
            if (ov < bv || (ov == bv && oi < bi)) { bv = ov; bi = oi; }
        }
        if (l == 0) g_knn[m*NN_ + r] = (u16)(bi & 4095);
        prevd = bv; previ = bi;
    }
}

// ------------------------------------------------- GEMM1 stats pass --------
__global__ __launch_bounds__(256) void stats1_kernel(
        const float* __restrict__ xyz, const float* __restrict__ points,
        const float* __restrict__ newxyz,
        const float* __restrict__ W1, const float* __restrict__ b1) {
    __shared__ float Xs[64][68];
    __shared__ float ps[16][128], pq[16][128];
    __shared__ float cen[4][3];
    __shared__ int rowp[64];
    const int t = threadIdx.x;
    const int blk = blockIdx.x;
    const int b = blk >> 8;
    const int g0 = blk * 64;
    if (t < 64)  rowp[t] = ((int)g_knn[g0 + t]) & 4095;
    if (t < 12)  cen[t/3][t%3] = newxyz[(blk*4 + t/3)*3 + (t%3)];
    __syncthreads();
    for (int e = t; e < 64*68; e += 256) {
        int r = e / 68, c = e % 68;
        int p = rowp[r];
        float v = 0.f;
        if (c < 3)         v = xyz[(b*N_ + p)*3 + c] - cen[r >> 4][c];
        else if (c < CIN_) v = points[(b*N_ + p)*64 + (c - 3)];
        Xs[r][c] = v;
    }
    __syncthreads();
    const int rg = t >> 4, cg = t & 15;
    const int r0 = rg * 4;
    float acc[4][8];
    #pragma unroll
    for (int j = 0; j < 4; ++j)
        #pragma unroll
        for (int i = 0; i < 8; ++i) acc[j][i] = 0.f;
    for (int q = 0; q < CIN_; ++q) {
        float xq[4];
        #pragma unroll
        for (int j = 0; j < 4; ++j) xq[j] = Xs[r0 + j][q];
        #pragma unroll
        for (int i = 0; i < 8; ++i) {
            float wv = W1[(cg + 16*i)*CIN_ + q];
            #pragma unroll
            for (int j = 0; j < 4; ++j) acc[j][i] += xq[j] * wv;
        }
    }
    #pragma unroll
    for (int i = 0; i < 8; ++i) {
        int o = cg + 16*i;
        float bias = b1[o];
        float s = 0.f, sq = 0.f;
        #pragma unroll
        for (int j = 0; j < 4; ++j) {
            float v = acc[j][i] + bias;
            s += v; sq += v*v;
        }
        ps[rg][o] = s; pq[rg][o] = sq;
    }
    __syncthreads();
    if (t < 128) {
        float ts = 0.f, tq = 0.f;
        #pragma unroll
        for (int g = 0; g < 16; ++g) { ts += ps[g][t]; tq += pq[g][t]; }
        g_part1[blk*256 + t] = ts;
        g_part1[blk*256 + 128 + t] = tq;
    }
}

// ------------------------------------------------------------ reduce -------
__global__ __launch_bounds__(256) void reduce1_kernel() {
    __shared__ float red[256];
    const int i = blockIdx.x, t = threadIdx.x;
    float s = 0.f;
    for (int r = t; r < NBLK; r += 256) s += g_part1[r*256 + i];
    red[t] = s;
    __syncthreads();
    for (int st = 128; st > 0; st >>= 1) {
        if (t < st) red[t] += red[t + st];
        __syncthreads();
    }
    if (t == 0) g_stats[i] = red[0];
}
__global__ __launch_bounds__(256) void reduce2_kernel() {
    __shared__ float red[256];
    const int i = blockIdx.x, t = threadIdx.x;
    float s = 0.f;
    for (int r = t; r < NBLK; r += 256) s += g_part2[r*256 + i];
    red[t] = s;
    __syncthreads();
    for (int st = 128; st > 0; st >>= 1) {
        if (t < st) red[t] += red[t + st];
        __syncthreads();
    }
    if (t == 0) g_stats[256 + i] = red[0];
}

// --------------------------------------------- fused GEMM1+BN1+GEMM2 -------
__global__ __launch_bounds__(256) void fused12_kernel(
        const float* __restrict__ xyz, const float* __restrict__ points,
        const float* __restrict__ newxyz,
        const float* __restrict__ W1, const float* __restrict__ b1,
        const float* __restrict__ g1, const float* __restrict__ be1,
        const float* __restrict__ W2, const float* __restrict__ b2) {
    __shared__ union {
        float Xs[64][68];
        struct { float ps[16][128], pq[16][128], pm[16][128]; } c;
    } u;
    __shared__ float h1s[64][128];
    __shared__ float cen[4][3];
    __shared__ int rowp[64];
    const int t = threadIdx.x;
    const int blk = blockIdx.x;
    const int b = blk >> 8;
    const int g0 = blk * 64;
    if (t < 64)  rowp[t] = ((int)g_knn[g0 + t]) & 4095;
    if (t < 12)  cen[t/3][t%3] = newxyz[(blk*4 + t/3)*3 + (t%3)];
    __syncthreads();
    for (int e = t; e < 64*68; e += 256) {
        int r = e / 68, c = e % 68;
        int p = rowp[r];
        float v = 0.f;
        if (c < 3)         v = xyz[(b*N_ + p)*3 + c] - cen[r >> 4][c];
        else if (c < CIN_) v = points[(b*N_ + p)*64 + (c - 3)];
        u.Xs[r][c] = v;
    }
    __syncthreads();
    const int rg = t >> 4, cg = t & 15;
    const int r0 = rg * 4;
    float acc[4][8];
    #pragma unroll
    for (int j = 0; j < 4; ++j)
        #pragma unroll
        for (int i = 0; i < 8; ++i) acc[j][i] = 0.f;
    for (int q = 0; q < CIN_; ++q) {
        float xq[4];
        #pragma unroll
        for (int j = 0; j < 4; ++j) xq[j] = u.Xs[r0 + j][q];
        #pragma unroll
        for (int i = 0; i < 8; ++i) {
            float wv = W1[(cg + 16*i)*CIN_ + q];
            #pragma unroll
            for (int j = 0; j < 4; ++j) acc[j][i] += xq[j] * wv;
        }
    }
    #pragma unroll
    for (int i = 0; i < 8; ++i) {
        int o = cg + 16*i;
        float mean = g_stats[o] * (1.f / BN_N);
        float var  = g_stats[128 + o] * (1.f / BN_N) - mean*mean;
        float sc   = (1.f / sqrtf(var + 1e-5f)) * g1[o];
        float bb   = be1[o];
        float bias = b1[o];
        #pragma unroll
        for (int j = 0; j < 4; ++j) {
            float v = acc[j][i] + bias;
            v = (v - mean) * sc + bb;
            v = fmaxf(v, 0.f);
            h1s[r0 + j][o] = v;
        }
    }
    __syncthreads();
    float acc2[4][8];
    #pragma unroll
    for (int j = 0; j < 4; ++j)
        #pragma unroll
        for (int i = 0; i < 8; ++i) acc2[j][i] = 0.f;
    for (int q = 0; q < C1_; ++q) {
        float xq[4];
        #pragma unroll
        for (int j = 0; j < 4; ++j) xq[j] = h1s[r0 + j][q];
        #pragma unroll
        for (int i = 0; i < 8; ++i) {
            float wv = W2[(cg + 16*i)*C1_ + q];
            #pragma unroll
            for (int j = 0; j < 4; ++j) acc2[j][i] += xq[j] * wv;
        }
    }
    #pragma unroll
    for (int i = 0; i < 8; ++i) {
        int o = cg + 16*i;
        float bias = b2[o];
        float s = 0.f, sq = 0.f, mx = -1e38f;
        #pragma unroll
        for (int j = 0; j < 4; ++j) {
            float v = acc2[j][i] + bias;
            s += v; sq += v*v; mx = fmaxf(mx, v);
        }
        u.c.ps[rg][o] = s; u.c.pq[rg][o] = sq; u.c.pm[rg][o] = mx;
    }
    __syncthreads();
    if (t < 128) {
        float ts = 0.f, tq = 0.f;
        #pragma unroll
        for (int g = 0; g < 16; ++g) { ts += u.c.ps[g][t]; tq += u.c.pq[g][t]; }
        g_part2[blk*256 + t] = ts;
        g_part2[blk*256 + 128 + t] = tq;
    }
    {
        const int o = t & 127, gg = t >> 7;
        for (int gp = gg; gp < 4; gp += 2) {
            float mx = u.c.pm[gp*4 + 0][o];
            mx = fmaxf(mx, u.c.pm[gp*4 + 1][o]);
            mx = fmaxf(mx, u.c.pm[gp*4 + 2][o]);
            mx = fmaxf(mx, u.c.pm[gp*4 + 3][o]);
            g_m2[(blk*4 + gp)*128 + o] = mx;
        }
    }
}

// ------------------------------------------------------------- finalize ----
__global__ __launch_bounds__(256) void final_kernel(
        const float* __restrict__ g2, const float* __restrict__ be2,
        float* __restrict__ outp) {
    __shared__ float mn[128], sc[128], bb[128];
    const int t = threadIdx.x;
    if (t < 128) {
        float mean = g_stats[256 + t] * (1.f / BN_N);
        float var  = g_stats[384 + t] * (1.f / BN_N) - mean*mean;
        float inv  = 1.f / sqrtf(var + 1e-5f);
        mn[t] = mean; sc[t] = inv * g2[t]; bb[t] = be2[t];
    }
    __syncthreads();
    const int m = blockIdx.x*2 + (t >> 7);
    const int c = t & 127;
    float v = (g_m2[m*128 + c] - mn[c]) * sc[c] + bb[c];
    v = fmaxf(v, 0.f);
    outp[m*C2_ + c] = v;
}

// -------------------------------------------------------------- launch -----
extern "C" void kernel_launch(void* const* d_in, const int* in_sizes, int n_in,
                              void* d_out, int out_size, void* d_ws, size_t ws_size,
                              hipStream_t stream) {
    const float* xyz    = (const float*)d_in[0];
    const float* points = (const float*)d_in[1];
    const float* W1     = (const float*)d_in[2];
    const float* b1     = (const float*)d_in[3];
    const float* g1     = (const float*)d_in[4];
    const float* be1    = (const float*)d_in[5];
    const float* W2     = (const float*)d_in[6];
    const float* b2     = (const float*)d_in[7];
    const float* g2     = (const float*)d_in[8];
    const float* be2    = (const float*)d_in[9];

    float* out_xyz = (float*)d_out;
    float* out_pts = (float*)d_out + B_*K_*3;

    (void)d_ws; (void)ws_size;

    fps_kernel<<<B_, 512, 0, stream>>>(xyz, out_xyz);
    knn_kernel<<<dim3(256, B_), 256, 0, stream>>>(xyz, out_xyz);
    stats1_kernel<<<NBLK, 256, 0, stream>>>(xyz, points, out_xyz, W1, b1);
    reduce1_kernel<<<256, 256, 0, stream>>>();
    fused12_kernel<<<NBLK, 256, 0, stream>>>(xyz, points, out_xyz,
                                             W1, b1, g1, be1, W2, b2);
    reduce2_kernel<<<256, 256, 0, stream>>>();
    final_kernel<<<B_*K_/2, 256, 0, stream>>>(g2, be2, out_pts);
}

// Round 12
// 1694.921 us; speedup vs baseline: 1.5978x; 1.4275x over previous
//
#include <hip/hip_runtime.h>

#define B_ 8
#define N_ 4096
#define K_ 1024
#define NN_ 16
#define C1_ 128
#define C2_ 128
#define CIN_ 67
#define NROWS (B_*K_*NN_)   // 131072
#define NBLK  (NROWS/64)    // 2048 GEMM tiles
#define BN_N 131072.0f

typedef unsigned short u16;

__device__ u16   g_knn[NROWS];
__device__ float g_part1[NBLK*256];
__device__ float g_part2[NBLK*256];
__device__ float g_stats[512];
__device__ float g_m2[B_*K_*C2_];
__device__ float g_W1T[68*128];    // W1 transposed [q][o], row 67 zeroed
__device__ float g_W2T[128*128];   // W2 transposed [q][o]

// ---------------------------------------------------- weight transpose -----
// Round-11 profile: W[(o)*C+q] broadcast loads touch 64 cache lines per wave
// instruction (~65k L1 transactions/wave in fused12). Transposed layout
// makes each load 1-2 lines. Exact copy -> numerics unchanged.
__global__ void transpose_w_kernel(const float* __restrict__ W1,
                                   const float* __restrict__ W2) {
    int t = blockIdx.x * 256 + threadIdx.x;
    if (t < 68*128) {
        int q = t >> 7, o = t & 127;
        g_W1T[t] = (q < CIN_) ? W1[o*CIN_ + q] : 0.f;
    }
    if (t < 128*128) {
        int q = t >> 7, o = t & 127;
        g_W2T[t] = W2[o*C1_ + q];
    }
}

// ---------------------------------------------------------------- FPS ------
// v3: 512 threads; ONE barrier per step (round-11's two-barrier version
// measured 2790 cyc/step). Double-buffered wave partials: step s writes
// wv[s&1] pre-barrier, reads post-barrier; step s+2's overwrite is ordered
// by barrier s+1. All threads redundantly reduce the 8 partials (broadcast
// LDS reads) and fetch the centroid. Selection semantics & contract-off
// distance order unchanged (passed r10/r11).
__global__ __launch_bounds__(512) void fps_kernel(const float* __restrict__ xyz,
                                                  float* __restrict__ out_xyz) {
    __shared__ float sx[N_*3];       // 48 KB xyz copy
    __shared__ float wv[2][8];
    __shared__ int   wi[2][8];
    const int b = blockIdx.x, t = threadIdx.x;
    const int l = t & 63, w = t >> 6;
    const float* xb = xyz + b * (N_ * 3);
    for (int e = t; e < N_*3; e += 512) sx[e] = xb[e];
    __syncthreads();
    float x0[8], y0[8], z0[8], dist[8];
    #pragma unroll
    for (int j = 0; j < 8; ++j) {
        int p = t * 8 + j;
        x0[j] = sx[p*3+0]; y0[j] = sx[p*3+1]; z0[j] = sx[p*3+2];
        dist[j] = 1e10f;
    }
    int far = 0;
    for (int s = 0; s < K_; ++s) {
        const float cx = sx[far*3+0], cy = sx[far*3+1], cz = sx[far*3+2];
        if (t == 0) {
            int o = (b*K_ + s) * 3;
            out_xyz[o+0] = cx; out_xyz[o+1] = cy; out_xyz[o+2] = cz;
        }
        float v = -1.f; int ib = 0;
        {
            #pragma clang fp contract(off)
            #pragma unroll
            for (int j = 0; j < 8; ++j) {
                float dx = x0[j]-cx, dy = y0[j]-cy, dz = z0[j]-cz;
                float dd = dx*dx; dd = dd + dy*dy; dd = dd + dz*dz;
                dd = fminf(dist[j], dd);
                dist[j] = dd;
                if (dd > v) { v = dd; ib = t*8 + j; }   // ascending j: first max
            }
        }
        #pragma unroll
        for (int off = 1; off <= 32; off <<= 1) {
            float ov = __shfl_xor(v, off);
            int   oi = __shfl_xor(ib, off);
            if (ov > v || (ov == v && oi < ib)) { v = ov; ib = oi; }
        }
        const int pb = s & 1;
        if (l == 0) { wv[pb][w] = v; wi[pb][w] = ib; }
        __syncthreads();                   // partials visible (only barrier)
        float bv = wv[pb][0]; int bi = wi[pb][0];
        #pragma unroll
        for (int ww = 1; ww < 8; ++ww) {
            float ov = wv[pb][ww];
            if (ov > bv) { bv = ov; bi = wi[pb][ww]; }   // waves ascending idx
        }
        far = bi & 4095;
    }
}

// ---------------------------------------------------------------- kNN ------
// One wave per center; 64 dists/lane in VGPRs; 16 lexicographic min
// extractions via shfl butterfly (no barriers). Unchanged from round 11.
__global__ __launch_bounds__(256) void knn_kernel(const float* __restrict__ xyz,
                                                  const float* __restrict__ newxyz) {
    __shared__ float px[N_], py[N_], pz[N_];
    const int b = blockIdx.y, t = threadIdx.x;
    const int l = t & 63, w = t >> 6;
    const int k = blockIdx.x * 4 + w;
    const int m = b*K_ + k;
    const float* xb = xyz + b * (N_ * 3);
    for (int p = t; p < N_; p += 256) {
        px[p] = xb[p*3+0]; py[p] = xb[p*3+1]; pz[p] = xb[p*3+2];
    }
    __syncthreads();
    const float cx = newxyz[m*3+0];
    const float cy = newxyz[m*3+1];
    const float cz = newxyz[m*3+2];
    float d[64];
    {
        #pragma clang fp contract(off)
        float sn = cx*cx; sn = sn + cy*cy; sn = sn + cz*cz;
        #pragma unroll
        for (int j = 0; j < 64; ++j) {
            int p = j*64 + l;
            float X = px[p], Y = py[p], Z = pz[p];
            float sp = X*X; sp = sp + Y*Y; sp = sp + Z*Z;
            float dt = cx*X; dt = dt + cy*Y; dt = dt + cz*Z;
            float t1 = sn + sp;
            d[j] = t1 - 2.0f*dt;
        }
    }
    float prevd = -1e38f; int previ = -1;
    for (int r = 0; r < NN_; ++r) {
        float bv = 1e38f; int bi = 0x7fffffff;
        #pragma unroll
        for (int j = 0; j < 64; ++j) {
            int p = j*64 + l;
            bool gt = (d[j] > prevd) || (d[j] == prevd && p > previ);
            bool lt = (d[j] < bv)   || (d[j] == bv   && p < bi);
            if (gt && lt) { bv = d[j]; bi = p; }
        }
        #pragma unroll
        for (int off = 1; off <= 32; off <<= 1) {
            float ov = __shfl_xor(bv, off);
            int   oi = __shfl_xor(bi, off);
            if (ov < bv || (ov == bv && oi < bi)) { bv = ov; bi = oi; }
        }
        if (l == 0) g_knn[m*NN_ + r] = (u16)(bi & 4095);
        prevd = bv; previ = bi;
    }
}

// ------------------------------------------------- GEMM1 stats pass --------
// W1T coalesced-broadcast loads + float4 LDS reads; partials unioned over Xs.
__global__ __launch_bounds__(256) void stats1_kernel(
        const float* __restrict__ xyz, const float* __restrict__ points,
        const float* __restrict__ newxyz, const float* __restrict__ b1) {
    __shared__ union {
        float Xs[64][68];                              // 17408 B
        struct { float ps[16][128], pq[16][128]; } c;  // 16384 B
    } u;
    __shared__ float cen[4][3];
    __shared__ int rowp[64];
    const int t = threadIdx.x;
    const int blk = blockIdx.x;
    const int b = blk >> 8;
    const int g0 = blk * 64;
    if (t < 64)  rowp[t] = ((int)g_knn[g0 + t]) & 4095;
    if (t < 12)  cen[t/3][t%3] = newxyz[(blk*4 + t/3)*3 + (t%3)];
    __syncthreads();
    for (int e = t; e < 64*68; e += 256) {
        int r = e / 68, c = e % 68;
        int p = rowp[r];
        float v = 0.f;
        if (c < 3)         v = xyz[(b*N_ + p)*3 + c] - cen[r >> 4][c];
        else if (c < CIN_) v = points[(b*N_ + p)*64 + (c - 3)];
        u.Xs[r][c] = v;
    }
    __syncthreads();
    const int rg = t >> 4, cg = t & 15;
    const int r0 = rg * 4;
    float acc[4][8];
    #pragma unroll
    for (int j = 0; j < 4; ++j)
        #pragma unroll
        for (int i = 0; i < 8; ++i) acc[j][i] = 0.f;
    for (int q4 = 0; q4 < 17; ++q4) {          // 68 = CIN padded; pads are 0
        float4 xv[4];
        #pragma unroll
        for (int j = 0; j < 4; ++j) xv[j] = *(const float4*)&u.Xs[r0 + j][q4*4];
        #pragma unroll
        for (int i = 0; i < 8; ++i) {
            int o = cg + 16*i;
            float w0 = g_W1T[(q4*4+0)*128 + o];
            float w1 = g_W1T[(q4*4+1)*128 + o];
            float w2 = g_W1T[(q4*4+2)*128 + o];
            float w3 = g_W1T[(q4*4+3)*128 + o];
            #pragma unroll
            for (int j = 0; j < 4; ++j) {
                float a = acc[j][i];
                a = a + xv[j].x*w0; a = a + xv[j].y*w1;
                a = a + xv[j].z*w2; a = a + xv[j].w*w3;
                acc[j][i] = a;
            }
        }
    }
    __syncthreads();   // Xs reads done -> union reusable
    #pragma unroll
    for (int i = 0; i < 8; ++i) {
        int o = cg + 16*i;
        float bias = b1[o];
        float s = 0.f, sq = 0.f;
        #pragma unroll
        for (int j = 0; j < 4; ++j) {
            float v = acc[j][i] + bias;
            s += v; sq += v*v;
        }
        u.c.ps[rg][o] = s; u.c.pq[rg][o] = sq;
    }
    __syncthreads();
    if (t < 128) {
        float ts = 0.f, tq = 0.f;
        #pragma unroll
        for (int g = 0; g < 16; ++g) { ts += u.c.ps[g][t]; tq += u.c.pq[g][t]; }
        g_part1[blk*256 + t] = ts;
        g_part1[blk*256 + 128 + t] = tq;
    }
}

// ------------------------------------------------------------ reduce -------
__global__ __launch_bounds__(256) void reduce1_kernel() {
    __shared__ float red[256];
    const int i = blockIdx.x, t = threadIdx.x;
    float s = 0.f;
    for (int r = t; r < NBLK; r += 256) s += g_part1[r*256 + i];
    red[t] = s;
    __syncthreads();
    for (int st = 128; st > 0; st >>= 1) {
        if (t < st) red[t] += red[t + st];
        __syncthreads();
    }
    if (t == 0) g_stats[i] = red[0];
}
__global__ __launch_bounds__(256) void reduce2_kernel() {
    __shared__ float red[256];
    const int i = blockIdx.x, t = threadIdx.x;
    float s = 0.f;
    for (int r = t; r < NBLK; r += 256) s += g_part2[r*256 + i];
    red[t] = s;
    __syncthreads();
    for (int st = 128; st > 0; st >>= 1) {
        if (t < st) red[t] += red[t + st];
        __syncthreads();
    }
    if (t == 0) g_stats[256 + i] = red[0];
}

// --------------------------------------------- fused GEMM1+BN1+GEMM2 -------
// W1T/W2T coalesced loads; float4 LDS reads; h1s padded to 132 (bank offset).
__global__ __launch_bounds__(256) void fused12_kernel(
        const float* __restrict__ xyz, const float* __restrict__ points,
        const float* __restrict__ newxyz,
        const float* __restrict__ b1, const float* __restrict__ g1,
        const float* __restrict__ be1, const float* __restrict__ b2) {
    __shared__ union {
        float Xs[64][68];                                         // 17408 B
        struct { float ps[16][128], pq[16][128], pm[16][128]; } c; // 24576 B
    } u;
    __shared__ float h1s[64][132];                                // 33792 B
    __shared__ float cen[4][3];
    __shared__ int rowp[64];
    const int t = threadIdx.x;
    const int blk = blockIdx.x;
    const int b = blk >> 8;
    const int g0 = blk * 64;
    if (t < 64)  rowp[t] = ((int)g_knn[g0 + t]) & 4095;
    if (t < 12)  cen[t/3][t%3] = newxyz[(blk*4 + t/3)*3 + (t%3)];
    __syncthreads();
    for (int e = t; e < 64*68; e += 256) {
        int r = e / 68, c = e % 68;
        int p = rowp[r];
        float v = 0.f;
        if (c < 3)         v = xyz[(b*N_ + p)*3 + c] - cen[r >> 4][c];
        else if (c < CIN_) v = points[(b*N_ + p)*64 + (c - 3)];
        u.Xs[r][c] = v;
    }
    __syncthreads();
    const int rg = t >> 4, cg = t & 15;
    const int r0 = rg * 4;
    // ---- GEMM1 ----
    float acc[4][8];
    #pragma unroll
    for (int j = 0; j < 4; ++j)
        #pragma unroll
        for (int i = 0; i < 8; ++i) acc[j][i] = 0.f;
    for (int q4 = 0; q4 < 17; ++q4) {
        float4 xv[4];
        #pragma unroll
        for (int j = 0; j < 4; ++j) xv[j] = *(const float4*)&u.Xs[r0 + j][q4*4];
        #pragma unroll
        for (int i = 0; i < 8; ++i) {
            int o = cg + 16*i;
            float w0 = g_W1T[(q4*4+0)*128 + o];
            float w1 = g_W1T[(q4*4+1)*128 + o];
            float w2 = g_W1T[(q4*4+2)*128 + o];
            float w3 = g_W1T[(q4*4+3)*128 + o];
            #pragma unroll
            for (int j = 0; j < 4; ++j) {
                float a = acc[j][i];
                a = a + xv[j].x*w0; a = a + xv[j].y*w1;
                a = a + xv[j].z*w2; a = a + xv[j].w*w3;
                acc[j][i] = a;
            }
        }
    }
    // BN1 + ReLU -> f32 h1 tile
    #pragma unroll
    for (int i = 0; i < 8; ++i) {
        int o = cg + 16*i;
        float mean = g_stats[o] * (1.f / BN_N);
        float var  = g_stats[128 + o] * (1.f / BN_N) - mean*mean;
        float sc   = (1.f / sqrtf(var + 1e-5f)) * g1[o];
        float bb   = be1[o];
        float bias = b1[o];
        #pragma unroll
        for (int j = 0; j < 4; ++j) {
            float v = acc[j][i] + bias;
            v = (v - mean) * sc + bb;
            v = fmaxf(v, 0.f);
            h1s[r0 + j][o] = v;
        }
    }
    __syncthreads();   // Xs reads done + h1s visible
    // ---- GEMM2 ----
    float acc2[4][8];
    #pragma unroll
    for (int j = 0; j < 4; ++j)
        #pragma unroll
        for (int i = 0; i < 8; ++i) acc2[j][i] = 0.f;
    for (int q4 = 0; q4 < 32; ++q4) {
        float4 xv[4];
        #pragma unroll
        for (int j = 0; j < 4; ++j) xv[j] = *(const float4*)&h1s[r0 + j][q4*4];
        #pragma unroll
        for (int i = 0; i < 8; ++i) {
            int o = cg + 16*i;
            float w0 = g_W2T[(q4*4+0)*128 + o];
            float w1 = g_W2T[(q4*4+1)*128 + o];
            float w2 = g_W2T[(q4*4+2)*128 + o];
            float w3 = g_W2T[(q4*4+3)*128 + o];
            #pragma unroll
            for (int j = 0; j < 4; ++j) {
                float a = acc2[j][i];
                a = a + xv[j].x*w0; a = a + xv[j].y*w1;
                a = a + xv[j].z*w2; a = a + xv[j].w*w3;
                acc2[j][i] = a;
            }
        }
    }
    // Epilogue: partials into union (Xs dead since h1s barrier)
    #pragma unroll
    for (int i = 0; i < 8; ++i) {
        int o = cg + 16*i;
        float bias = b2[o];
        float s = 0.f, sq = 0.f, mx = -1e38f;
        #pragma unroll
        for (int j = 0; j < 4; ++j) {
            float v = acc2[j][i] + bias;
            s += v; sq += v*v; mx = fmaxf(mx, v);
        }
        u.c.ps[rg][o] = s; u.c.pq[rg][o] = sq; u.c.pm[rg][o] = mx;
    }
    __syncthreads();
    if (t < 128) {
        float ts = 0.f, tq = 0.f;
        #pragma unroll
        for (int g = 0; g < 16; ++g) { ts += u.c.ps[g][t]; tq += u.c.pq[g][t]; }
        g_part2[blk*256 + t] = ts;
        g_part2[blk*256 + 128 + t] = tq;
    }
    {
        const int o = t & 127, gg = t >> 7;
        for (int gp = gg; gp < 4; gp += 2) {
            float mx = u.c.pm[gp*4 + 0][o];
            mx = fmaxf(mx, u.c.pm[gp*4 + 1][o]);
            mx = fmaxf(mx, u.c.pm[gp*4 + 2][o]);
            mx = fmaxf(mx, u.c.pm[gp*4 + 3][o]);
            g_m2[(blk*4 + gp)*128 + o] = mx;
        }
    }
}

// ------------------------------------------------------------- finalize ----
__global__ __launch_bounds__(256) void final_kernel(
        const float* __restrict__ g2, const float* __restrict__ be2,
        float* __restrict__ outp) {
    __shared__ float mn[128], sc[128], bb[128];
    const int t = threadIdx.x;
    if (t < 128) {
        float mean = g_stats[256 + t] * (1.f / BN_N);
        float var  = g_stats[384 + t] * (1.f / BN_N) - mean*mean;
        float inv  = 1.f / sqrtf(var + 1e-5f);
        mn[t] = mean; sc[t] = inv * g2[t]; bb[t] = be2[t];
    }
    __syncthreads();
    const int m = blockIdx.x*2 + (t >> 7);
    const int c = t & 127;
    float v = (g_m2[m*128 + c] - mn[c]) * sc[c] + bb[c];
    v = fmaxf(v, 0.f);
    outp[m*C2_ + c] = v;
}

// -------------------------------------------------------------- launch -----
extern "C" void kernel_launch(void* const* d_in, const int* in_sizes, int n_in,
                              void* d_out, int out_size, void* d_ws, size_t ws_size,
                              hipStream_t stream) {
    const float* xyz    = (const float*)d_in[0];
    const float* points = (const float*)d_in[1];
    const float* W1     = (const float*)d_in[2];
    const float* b1     = (const float*)d_in[3];
    const float* g1     = (const float*)d_in[4];
    const float* be1    = (const float*)d_in[5];
    const float* W2     = (const float*)d_in[6];
    const float* b2     = (const float*)d_in[7];
    const float* g2     = (const float*)d_in[8];
    const float* be2    = (const float*)d_in[9];

    float* out_xyz = (float*)d_out;
    float* out_pts = (float*)d_out + B_*K_*3;

    (void)d_ws; (void)ws_size;

    transpose_w_kernel<<<64, 256, 0, stream>>>(W1, W2);
    fps_kernel<<<B_, 512, 0, stream>>>(xyz, out_xyz);
    knn_kernel<<<dim3(256, B_), 256, 0, stream>>>(xyz, out_xyz);
    stats1_kernel<<<NBLK, 256, 0, stream>>>(xyz, points, out_xyz, b1);
    reduce1_kernel<<<256, 256, 0, stream>>>();
    fused12_kernel<<<NBLK, 256, 0, stream>>>(xyz, points, out_xyz,
                                             b1, g1, be1, b2);
    reduce2_kernel<<<256, 256, 0, stream>>>();
    final_kernel<<<B_*K_/2, 256, 0, stream>>>(g2, be2, out_pts);
}

// Round 13
// 1378.808 us; speedup vs baseline: 1.9641x; 1.2293x over previous
//
#include <hip/hip_runtime.h>

#define B_ 8
#define N_ 4096
#define K_ 1024
#define NN_ 16
#define C1_ 128
#define C2_ 128
#define CIN_ 67
#define NROWS (B_*K_*NN_)   // 131072
#define NBLK  (NROWS/64)    // 2048 GEMM tiles
#define BN_N 131072.0f

typedef unsigned short u16;

__device__ u16   g_knn[NROWS];
__device__ float g_part1[NBLK*256];
__device__ float g_part2[NBLK*256];
__device__ float g_stats[512];
__device__ float g_m2[B_*K_*C2_];
__device__ float g_W1T[68*128];    // W1 transposed [q][o], row 67 zeroed
__device__ float g_W2T[128*128];   // W2 transposed [q][o]

// --------------------------------------------------- DPP wave reduction ----
// rocPRIM-style reduce-to-lane-63: row_shr 1/2/4/8 then row_bcast15/31.
// v_mov_dpp is VALU-latency (~4 cyc) vs ds_bpermute (~100 cyc) that
// __shfl_xor emits — round-12 fps spent most of its 2707 cyc/step there.
// bound_ctrl=false + old=self => invalid lanes self-compare (harmless).
template<int CTRL>
static __device__ __forceinline__ void dpp_max_step(float& v, int& ib) {
    int vi = __float_as_int(v);
    int ov = __builtin_amdgcn_update_dpp(vi, vi, CTRL, 0xf, 0xf, false);
    int oi = __builtin_amdgcn_update_dpp(ib, ib, CTRL, 0xf, 0xf, false);
    float of = __int_as_float(ov);
    if (of > v || (of == v && oi < ib)) { v = of; ib = oi; }
}
template<int CTRL>
static __device__ __forceinline__ void dpp_min_step(float& v, int& ib) {
    int vi = __float_as_int(v);
    int ov = __builtin_amdgcn_update_dpp(vi, vi, CTRL, 0xf, 0xf, false);
    int oi = __builtin_amdgcn_update_dpp(ib, ib, CTRL, 0xf, 0xf, false);
    float of = __int_as_float(ov);
    if (of < v || (of == v && oi < ib)) { v = of; ib = oi; }
}
static __device__ __forceinline__ void wave_reduce_max(float& v, int& ib) {
    dpp_max_step<0x111>(v, ib);   // row_shr:1
    dpp_max_step<0x112>(v, ib);   // row_shr:2
    dpp_max_step<0x114>(v, ib);   // row_shr:4
    dpp_max_step<0x118>(v, ib);   // row_shr:8
    dpp_max_step<0x142>(v, ib);   // row_bcast:15
    dpp_max_step<0x143>(v, ib);   // row_bcast:31  -> lane 63 holds winner
}
static __device__ __forceinline__ void wave_reduce_min(float& v, int& ib) {
    dpp_min_step<0x111>(v, ib);
    dpp_min_step<0x112>(v, ib);
    dpp_min_step<0x114>(v, ib);
    dpp_min_step<0x118>(v, ib);
    dpp_min_step<0x142>(v, ib);
    dpp_min_step<0x143>(v, ib);
}

// ---------------------------------------------------- weight transpose -----
__global__ void transpose_w_kernel(const float* __restrict__ W1,
                                   const float* __restrict__ W2) {
    int t = blockIdx.x * 256 + threadIdx.x;
    if (t < 68*128) {
        int q = t >> 7, o = t & 127;
        g_W1T[t] = (q < CIN_) ? W1[o*CIN_ + q] : 0.f;
    }
    if (t < 128*128) {
        int q = t >> 7, o = t & 127;
        g_W2T[t] = W2[o*C1_ + q];
    }
}

// ---------------------------------------------------------------- FPS ------
// v4: 256 threads, 16 pts/lane; DPP in-wave reduce (no ds_bpermute), lane 63
// writes the wave partial (4 waves), double-buffered -> ONE barrier/step.
// Selection semantics & contract-off distance order unchanged (passed
// r10-r12): per-lane first-max over ascending indices, cross-lane tie ->
// min index; comparator is associative so any reduction tree is exact.
__global__ __launch_bounds__(256) void fps_kernel(const float* __restrict__ xyz,
                                                  float* __restrict__ out_xyz) {
    __shared__ float sx[N_*3];       // 48 KB xyz copy
    __shared__ float wv[2][4];
    __shared__ int   wi[2][4];
    const int b = blockIdx.x, t = threadIdx.x;
    const int l = t & 63, w = t >> 6;
    const float* xb = xyz + b * (N_ * 3);
    for (int e = t; e < N_*3; e += 256) sx[e] = xb[e];
    __syncthreads();
    float x0[16], y0[16], z0[16], dist[16];
    #pragma unroll
    for (int j = 0; j < 16; ++j) {
        int p = t * 16 + j;
        x0[j] = sx[p*3+0]; y0[j] = sx[p*3+1]; z0[j] = sx[p*3+2];
        dist[j] = 1e10f;
    }
    int far = 0;
    for (int s = 0; s < K_; ++s) {
        const float cx = sx[far*3+0], cy = sx[far*3+1], cz = sx[far*3+2];
        if (t == 0) {
            int o = (b*K_ + s) * 3;
            out_xyz[o+0] = cx; out_xyz[o+1] = cy; out_xyz[o+2] = cz;
        }
        float v = -1.f; int ib = 0;
        {
            #pragma clang fp contract(off)
            #pragma unroll
            for (int j = 0; j < 16; ++j) {
                float dx = x0[j]-cx, dy = y0[j]-cy, dz = z0[j]-cz;
                float dd = dx*dx; dd = dd + dy*dy; dd = dd + dz*dz;
                dd = fminf(dist[j], dd);
                dist[j] = dd;
                if (dd > v) { v = dd; ib = t*16 + j; }   // ascending j: first max
            }
        }
        wave_reduce_max(v, ib);
        const int pb = s & 1;
        if (l == 63) { wv[pb][w] = v; wi[pb][w] = ib; }
        __syncthreads();                   // partials visible (only barrier)
        float bv = wv[pb][0]; int bi = wi[pb][0];
        #pragma unroll
        for (int ww = 1; ww < 4; ++ww) {
            float ov = wv[pb][ww];
            if (ov > bv) { bv = ov; bi = wi[pb][ww]; }   // waves ascending idx
        }
        far = bi & 4095;
    }
}

// ---------------------------------------------------------------- kNN ------
// One wave per center; 64 dists/lane; 16 lexicographic min extractions via
// DPP reduce + readlane(63) broadcast (uniform), no barriers in the loop.
__global__ __launch_bounds__(256) void knn_kernel(const float* __restrict__ xyz,
                                                  const float* __restrict__ newxyz) {
    __shared__ float px[N_], py[N_], pz[N_];
    const int b = blockIdx.y, t = threadIdx.x;
    const int l = t & 63, w = t >> 6;
    const int k = blockIdx.x * 4 + w;
    const int m = b*K_ + k;
    const float* xb = xyz + b * (N_ * 3);
    for (int p = t; p < N_; p += 256) {
        px[p] = xb[p*3+0]; py[p] = xb[p*3+1]; pz[p] = xb[p*3+2];
    }
    __syncthreads();
    const float cx = newxyz[m*3+0];
    const float cy = newxyz[m*3+1];
    const float cz = newxyz[m*3+2];
    float d[64];
    {
        #pragma clang fp contract(off)
        float sn = cx*cx; sn = sn + cy*cy; sn = sn + cz*cz;
        #pragma unroll
        for (int j = 0; j < 64; ++j) {
            int p = j*64 + l;
            float X = px[p], Y = py[p], Z = pz[p];
            float sp = X*X; sp = sp + Y*Y; sp = sp + Z*Z;
            float dt = cx*X; dt = dt + cy*Y; dt = dt + cz*Z;
            float t1 = sn + sp;
            d[j] = t1 - 2.0f*dt;
        }
    }
    float prevd = -1e38f; int previ = -1;
    for (int r = 0; r < NN_; ++r) {
        float bv = 1e38f; int bi = 0x7fffffff;
        #pragma unroll
        for (int j = 0; j < 64; ++j) {
            int p = j*64 + l;
            bool gt = (d[j] > prevd) || (d[j] == prevd && p > previ);
            bool lt = (d[j] < bv)   || (d[j] == bv   && p < bi);
            if (gt && lt) { bv = d[j]; bi = p; }
        }
        wave_reduce_min(bv, bi);
        previ = __builtin_amdgcn_readlane(bi, 63);                      // uniform
        prevd = __int_as_float(__builtin_amdgcn_readlane(__float_as_int(bv), 63));
        if (l == 0) g_knn[m*NN_ + r] = (u16)(previ & 4095);
    }
}

// ------------------------------------------------- GEMM1 stats pass --------
__global__ __launch_bounds__(256) void stats1_kernel(
        const float* __restrict__ xyz, const float* __restrict__ points,
        const float* __restrict__ newxyz, const float* __restrict__ b1) {
    __shared__ union {
        float Xs[64][68];
        struct { float ps[16][128], pq[16][128]; } c;
    } u;
    __shared__ float cen[4][3];
    __shared__ int rowp[64];
    const int t = threadIdx.x;
    const int blk = blockIdx.x;
    const int b = blk >> 8;
    const int g0 = blk * 64;
    if (t < 64)  rowp[t] = ((int)g_knn[g0 + t]) & 4095;
    if (t < 12)  cen[t/3][t%3] = newxyz[(blk*4 + t/3)*3 + (t%3)];
    __syncthreads();
    for (int e = t; e < 64*68; e += 256) {
        int r = e / 68, c = e % 68;
        int p = rowp[r];
        float v = 0.f;
        if (c < 3)         v = xyz[(b*N_ + p)*3 + c] - cen[r >> 4][c];
        else if (c < CIN_) v = points[(b*N_ + p)*64 + (c - 3)];
        u.Xs[r][c] = v;
    }
    __syncthreads();
    const int rg = t >> 4, cg = t & 15;
    const int r0 = rg * 4;
    float acc[4][8];
    #pragma unroll
    for (int j = 0; j < 4; ++j)
        #pragma unroll
        for (int i = 0; i < 8; ++i) acc[j][i] = 0.f;
    for (int q4 = 0; q4 < 17; ++q4) {
        float4 xv[4];
        #pragma unroll
        for (int j = 0; j < 4; ++j) xv[j] = *(const float4*)&u.Xs[r0 + j][q4*4];
        #pragma unroll
        for (int i = 0; i < 8; ++i) {
            int o = cg + 16*i;
            float w0 = g_W1T[(q4*4+0)*128 + o];
            float w1 = g_W1T[(q4*4+1)*128 + o];
            float w2 = g_W1T[(q4*4+2)*128 + o];
            float w3 = g_W1T[(q4*4+3)*128 + o];
            #pragma unroll
            for (int j = 0; j < 4; ++j) {
                float a = acc[j][i];
                a = a + xv[j].x*w0; a = a + xv[j].y*w1;
                a = a + xv[j].z*w2; a = a + xv[j].w*w3;
                acc[j][i] = a;
            }
        }
    }
    __syncthreads();
    #pragma unroll
    for (int i = 0; i < 8; ++i) {
        int o = cg + 16*i;
        float bias = b1[o];
        float s = 0.f, sq = 0.f;
        #pragma unroll
        for (int j = 0; j < 4; ++j) {
            float v = acc[j][i] + bias;
            s += v; sq += v*v;
        }
        u.c.ps[rg][o] = s; u.c.pq[rg][o] = sq;
    }
    __syncthreads();
    if (t < 128) {
        float ts = 0.f, tq = 0.f;
        #pragma unroll
        for (int g = 0; g < 16; ++g) { ts += u.c.ps[g][t]; tq += u.c.pq[g][t]; }
        g_part1[blk*256 + t] = ts;
        g_part1[blk*256 + 128 + t] = tq;
    }
}

// ------------------------------------------------------------ reduce -------
__global__ __launch_bounds__(256) void reduce1_kernel() {
    __shared__ float red[256];
    const int i = blockIdx.x, t = threadIdx.x;
    float s = 0.f;
    for (int r = t; r < NBLK; r += 256) s += g_part1[r*256 + i];
    red[t] = s;
    __syncthreads();
    for (int st = 128; st > 0; st >>= 1) {
        if (t < st) red[t] += red[t + st];
        __syncthreads();
    }
    if (t == 0) g_stats[i] = red[0];
}
__global__ __launch_bounds__(256) void reduce2_kernel() {
    __shared__ float red[256];
    const int i = blockIdx.x, t = threadIdx.x;
    float s = 0.f;
    for (int r = t; r < NBLK; r += 256) s += g_part2[r*256 + i];
    red[t] = s;
    __syncthreads();
    for (int st = 128; st > 0; st >>= 1) {
        if (t < st) red[t] += red[t + st];
        __syncthreads();
    }
    if (t == 0) g_stats[256 + i] = red[0];
}

// --------------------------------------------- fused GEMM1+BN1+GEMM2 -------
__global__ __launch_bounds__(256) void fused12_kernel(
        const float* __restrict__ xyz, const float* __restrict__ points,
        const float* __restrict__ newxyz,
        const float* __restrict__ b1, const float* __restrict__ g1,
        const float* __restrict__ be1, const float* __restrict__ b2) {
    __shared__ union {
        float Xs[64][68];
        struct { float ps[16][128], pq[16][128], pm[16][128]; } c;
    } u;
    __shared__ float h1s[64][132];
    __shared__ float cen[4][3];
    __shared__ int rowp[64];
    const int t = threadIdx.x;
    const int blk = blockIdx.x;
    const int b = blk >> 8;
    const int g0 = blk * 64;
    if (t < 64)  rowp[t] = ((int)g_knn[g0 + t]) & 4095;
    if (t < 12)  cen[t/3][t%3] = newxyz[(blk*4 + t/3)*3 + (t%3)];
    __syncthreads();
    for (int e = t; e < 64*68; e += 256) {
        int r = e / 68, c = e % 68;
        int p = rowp[r];
        float v = 0.f;
        if (c < 3)         v = xyz[(b*N_ + p)*3 + c] - cen[r >> 4][c];
        else if (c < CIN_) v = points[(b*N_ + p)*64 + (c - 3)];
        u.Xs[r][c] = v;
    }
    __syncthreads();
    const int rg = t >> 4, cg = t & 15;
    const int r0 = rg * 4;
    // ---- GEMM1 ----
    float acc[4][8];
    #pragma unroll
    for (int j = 0; j < 4; ++j)
        #pragma unroll
        for (int i = 0; i < 8; ++i) acc[j][i] = 0.f;
    for (int q4 = 0; q4 < 17; ++q4) {
        float4 xv[4];
        #pragma unroll
        for (int j = 0; j < 4; ++j) xv[j] = *(const float4*)&u.Xs[r0 + j][q4*4];
        #pragma unroll
        for (int i = 0; i < 8; ++i) {
            int o = cg + 16*i;
            float w0 = g_W1T[(q4*4+0)*128 + o];
            float w1 = g_W1T[(q4*4+1)*128 + o];
            float w2 = g_W1T[(q4*4+2)*128 + o];
            float w3 = g_W1T[(q4*4+3)*128 + o];
            #pragma unroll
            for (int j = 0; j < 4; ++j) {
                float a = acc[j][i];
                a = a + xv[j].x*w0; a = a + xv[j].y*w1;
                a = a + xv[j].z*w2; a = a + xv[j].w*w3;
                acc[j][i] = a;
            }
        }
    }
    // BN1 + ReLU -> f32 h1 tile
    #pragma unroll
    for (int i = 0; i < 8; ++i) {
        int o = cg + 16*i;
        float mean = g_stats[o] * (1.f / BN_N);
        float var  = g_stats[128 + o] * (1.f / BN_N) - mean*mean;
        float sc   = (1.f / sqrtf(var + 1e-5f)) * g1[o];
        float bb   = be1[o];
        float bias = b1[o];
        #pragma unroll
        for (int j = 0; j < 4; ++j) {
            float v = acc[j][i] + bias;
            v = (v - mean) * sc + bb;
            v = fmaxf(v, 0.f);
            h1s[r0 + j][o] = v;
        }
    }
    __syncthreads();
    // ---- GEMM2 ----
    float acc2[4][8];
    #pragma unroll
    for (int j = 0; j < 4; ++j)
        #pragma unroll
        for (int i = 0; i < 8; ++i) acc2[j][i] = 0.f;
    for (int q4 = 0; q4 < 32; ++q4) {
        float4 xv[4];
        #pragma unroll
        for (int j = 0; j < 4; ++j) xv[j] = *(const float4*)&h1s[r0 + j][q4*4];
        #pragma unroll
        for (int i = 0; i < 8; ++i) {
            int o = cg + 16*i;
            float w0 = g_W2T[(q4*4+0)*128 + o];
            float w1 = g_W2T[(q4*4+1)*128 + o];
            float w2 = g_W2T[(q4*4+2)*128 + o];
            float w3 = g_W2T[(q4*4+3)*128 + o];
            #pragma unroll
            for (int j = 0; j < 4; ++j) {
                float a = acc2[j][i];
                a = a + xv[j].x*w0; a = a + xv[j].y*w1;
                a = a + xv[j].z*w2; a = a + xv[j].w*w3;
                acc2[j][i] = a;
            }
        }
    }
    #pragma unroll
    for (int i = 0; i < 8; ++i) {
        int o = cg + 16*i;
        float bias = b2[o];
        float s = 0.f, sq = 0.f, mx = -1e38f;
        #pragma unroll
        for (int j = 0; j < 4; ++j) {
            float v = acc2[j][i] + bias;
            s += v; sq += v*v; mx = fmaxf(mx, v);
        }
        u.c.ps[rg][o] = s; u.c.pq[rg][o] = sq; u.c.pm[rg][o] = mx;
    }
    __syncthreads();
    if (t < 128) {
        float ts = 0.f, tq = 0.f;
        #pragma unroll
        for (int g = 0; g < 16; ++g) { ts += u.c.ps[g][t]; tq += u.c.pq[g][t]; }
        g_part2[blk*256 + t] = ts;
        g_part2[blk*256 + 128 + t] = tq;
    }
    {
        const int o = t & 127, gg = t >> 7;
        for (int gp = gg; gp < 4; gp += 2) {
            float mx = u.c.pm[gp*4 + 0][o];
            mx = fmaxf(mx, u.c.pm[gp*4 + 1][o]);
            mx = fmaxf(mx, u.c.pm[gp*4 + 2][o]);
            mx = fmaxf(mx, u.c.pm[gp*4 + 3][o]);
            g_m2[(blk*4 + gp)*128 + o] = mx;
        }
    }
}

// ------------------------------------------------------------- finalize ----
__global__ __launch_bounds__(256) void final_kernel(
        const float* __restrict__ g2, const float* __restrict__ be2,
        float* __restrict__ outp) {
    __shared__ float mn[128], sc[128], bb[128];
    const int t = threadIdx.x;
    if (t < 128) {
        float mean = g_stats[256 + t] * (1.f / BN_N);
        float var  = g_stats[384 + t] * (1.f / BN_N) - mean*mean;
        float inv  = 1.f / sqrtf(var + 1e-5f);
        mn[t] = mean; sc[t] = inv * g2[t]; bb[t] = be2[t];
    }
    __syncthreads();
    const int m = blockIdx.x*2 + (t >> 7);
    const int c = t & 127;
    float v = (g_m2[m*128 + c] - mn[c]) * sc[c] + bb[c];
    v = fmaxf(v, 0.f);
    outp[m*C2_ + c] = v;
}

// -------------------------------------------------------------- launch -----
extern "C" void kernel_launch(void* const* d_in, const int* in_sizes, int n_in,
                              void* d_out, int out_size, void* d_ws, size_t ws_size,
                              hipStream_t stream) {
    const float* xyz    = (const float*)d_in[0];
    const float* points = (const float*)d_in[1];
    const float* W1     = (const float*)d_in[2];
    const float* b1     = (const float*)d_in[3];
    const float* g1     = (const float*)d_in[4];
    const float* be1    = (const float*)d_in[5];
    const float* W2     = (const float*)d_in[6];
    const float* b2     = (const float*)d_in[7];
    const float* g2     = (const float*)d_in[8];
    const float* be2    = (const float*)d_in[9];

    float* out_xyz = (float*)d_out;
    float* out_pts = (float*)d_out + B_*K_*3;

    (void)d_ws; (void)ws_size;

    transpose_w_kernel<<<64, 256, 0, stream>>>(W1, W2);
    fps_kernel<<<B_, 256, 0, stream>>>(xyz, out_xyz);
    knn_kernel<<<dim3(256, B_), 256, 0, stream>>>(xyz, out_xyz);
    stats1_kernel<<<NBLK, 256, 0, stream>>>(xyz, points, out_xyz, b1);
    reduce1_kernel<<<256, 256, 0, stream>>>();
    fused12_kernel<<<NBLK, 256, 0, stream>>>(xyz, points, out_xyz,
                                             b1, g1, be1, b2);
    reduce2_kernel<<<256, 256, 0, stream>>>();
    final_kernel<<<B_*K_/2, 256, 0, stream>>>(g2, be2, out_pts);
}